// Round 5
// baseline (116.676 us; speedup 1.0000x reference)
//
#include <hip/hip_runtime.h>
#include <math.h>

// Problem constants
#define NN   768
#define HH   300
#define HP   320            // padded hidden dim (multiple of 64)
#define KD   768

// ---- ws float layout (h-matrices stored [i][h], 320 h per row) ----
// P2: [2 g][4 ks][768 i][320 h] gemm partials  @ 0
// CF2 [768][320] = hx  (i-major)               @ 1966080
// AF2 [768][320] = hy[perm]+b1 (i-major)       @ 2211840
// RS  [16 jb][768] per-jblock exp-rowsums      @ 2457600
// T0  t0 contributions[768]                    @ 2469888
#define P_OFF    0
#define PKS_STR  245760           // 768*320
#define PG_STR   983040           // 4*PKS_STR
#define CF_OFF   1966080
#define AF_OFF   2211840
#define RS_OFF   2457600
#define T0_OFF   2469888

// ========== K1: both GEMMs, transposed-to-[i][h] out, K-split 4 =============
// (byte-identical to round 4)
__global__ __launch_bounds__(256) void k1_gemm(
    const float* __restrict__ x, const float* __restrict__ y,
    const int* __restrict__ perm, const float* __restrict__ W1,
    float* __restrict__ wsf)
{
    const int tid = threadIdx.x;
    const int tx = tid & 15;          // i: {4tx..} u {64+4tx..}
    const int ty = tid >> 4;          // h: 4ty..4ty+3
    const int i0 = blockIdx.x * 128;
    const int h0 = blockIdx.y * 64;
    const int g  = blockIdx.z & 1;
    const int ks = blockIdx.z >> 1;   // 0..3
    const int kbeg = ks * 192;

    const float* src = g ? y : x;
    const int koff = g ? KD : 0;

    __shared__ float Xt[32][132];     // Xt[k][i]
    __shared__ float Wt[32][68];      // Wt[k][h]

    float acc[4][8];
    #pragma unroll
    for (int r = 0; r < 4; ++r)
        #pragma unroll
        for (int cc = 0; cc < 8; ++cc) acc[r][cc] = 0.f;

    const int kq = (tid & 7) << 2;
    const float* xp[4];
    int xr[4];
    #pragma unroll
    for (int it = 0; it < 4; ++it) {
        int row = ((tid + it*256) >> 3);          // 0..127
        int gr = i0 + row;
        if (g) gr = perm[gr];
        xp[it] = src + (size_t)gr * KD + kbeg + kq;
        xr[it] = row;
    }
    const float* wp[2];
    int wr[2]; bool wv[2];
    #pragma unroll
    for (int it = 0; it < 2; ++it) {
        int hrow = ((tid + it*256) >> 3);         // 0..63
        int hg = h0 + hrow;
        wv[it] = hg < HH;
        wp[it] = W1 + (size_t)(wv[it] ? hg : 0) * (2*KD) + koff + kbeg + kq;
        wr[it] = hrow;
    }

    for (int kb = 0; kb < 192; kb += 32) {
        float4 xv[4], wvv[2];
        #pragma unroll
        for (int it = 0; it < 4; ++it) xv[it] = *(const float4*)(xp[it] + kb);
        #pragma unroll
        for (int it = 0; it < 2; ++it) {
            wvv[it] = *(const float4*)(wp[it] + kb);
            if (!wv[it]) wvv[it] = make_float4(0,0,0,0);
        }
        if (kb) __syncthreads();
        #pragma unroll
        for (int it = 0; it < 4; ++it) {
            Xt[kq+0][xr[it]] = xv[it].x; Xt[kq+1][xr[it]] = xv[it].y;
            Xt[kq+2][xr[it]] = xv[it].z; Xt[kq+3][xr[it]] = xv[it].w;
        }
        #pragma unroll
        for (int it = 0; it < 2; ++it) {
            Wt[kq+0][wr[it]] = wvv[it].x; Wt[kq+1][wr[it]] = wvv[it].y;
            Wt[kq+2][wr[it]] = wvv[it].z; Wt[kq+3][wr[it]] = wvv[it].w;
        }
        __syncthreads();

        #pragma unroll 8
        for (int k = 0; k < 32; ++k) {
            float4 a   = *(const float4*)&Wt[k][4*ty];
            float4 b0  = *(const float4*)&Xt[k][4*tx];
            float4 b1v = *(const float4*)&Xt[k][64 + 4*tx];
            float ar[4] = {a.x, a.y, a.z, a.w};
            float br[8] = {b0.x, b0.y, b0.z, b0.w, b1v.x, b1v.y, b1v.z, b1v.w};
            #pragma unroll
            for (int r = 0; r < 4; ++r)
                #pragma unroll
                for (int cc = 0; cc < 8; ++cc)
                    acc[r][cc] = fmaf(ar[r], br[cc], acc[r][cc]);
        }
    }

    float* dst = wsf + P_OFF + (size_t)(g*4 + ks) * PKS_STR;
    #pragma unroll
    for (int cc = 0; cc < 8; ++cc) {
        int i = i0 + ((cc >> 2) ? 64 : 0) + 4*tx + (cc & 3);
        float4 v = make_float4(acc[0][cc], acc[1][cc], acc[2][cc], acc[3][cc]);
        *(float4*)(dst + (size_t)i * HP + h0 + 4*ty) = v;
    }
}

// ===== K1b: sum 4 K-partials -> CF2/AF2 ([i][h]); A += b1 ===================
// (byte-identical to round 4)
__global__ __launch_bounds__(256) void k1b_combine(
    const float* __restrict__ b1, float* __restrict__ wsf)
{
    int idx = blockIdx.x * 256 + threadIdx.x;   // 480 blocks -> 122880
    int g = idx >= 61440;
    int rem = idx - g * 61440;
    int i = rem / 80;                 // 0..767
    int h4 = (rem % 80) * 4;          // 0..316

    float4 o = make_float4(0.f,0.f,0.f,0.f);
    const float* p = wsf + P_OFF + (size_t)g * PG_STR + (size_t)i * HP + h4;
    #pragma unroll
    for (int ks = 0; ks < 4; ++ks) {
        float4 v = *(const float4*)(p + (size_t)ks * PKS_STR);
        o.x += v.x; o.y += v.y; o.z += v.z; o.w += v.w;
    }
    if (g && h4 < HH) {               // HH divisible by 4 -> whole quad valid
        float4 bv = *(const float4*)(b1 + h4);
        o.x += bv.x; o.y += bv.y; o.z += bv.z; o.w += bv.w;
    }
    float* dst = wsf + (g ? AF_OFF : CF_OFF) + (size_t)i * HP + h4;
    *(float4*)dst = o;
}

// ======== K2: pairwise relu-dot, fused exp+rowsum, 512-thr h-split ==========
// tile 48i x 48j, grid (16 j, 16 i) = 256 blocks x 512 threads; h-split:
// waves 0-3 h[0,152), waves 4-7 h[152,304) (pad rows zero => contribute 0).
// CHANGES vs r4: (1) quad-major LDS [q][i][4] so the 16-lane C-read is a
// CONTIGUOUS 256B segment (k1's proven pattern) instead of a 16-row gather;
// +49 pad keeps staging writes ~5-way. (2) explicit ping-pong software
// pipeline: quad q+1's 7 ds_read_b128 are issued BEFORE quad q's 108 VALU
// ops, giving a guaranteed 216-cyc issue distance to hide LDS latency
// (the compiler refused to pipeline on its own: VGPR_Count was 24).
#define ROW(wv, a0v, a1v, a2v, c0v, c1v, c2v)                      \
    acc00 = fmaf(fmaxf(a0v + c0v, 0.f), wv, acc00);                \
    acc01 = fmaf(fmaxf(a0v + c1v, 0.f), wv, acc01);                \
    acc02 = fmaf(fmaxf(a0v + c2v, 0.f), wv, acc02);                \
    acc10 = fmaf(fmaxf(a1v + c0v, 0.f), wv, acc10);                \
    acc11 = fmaf(fmaxf(a1v + c1v, 0.f), wv, acc11);                \
    acc12 = fmaf(fmaxf(a1v + c2v, 0.f), wv, acc12);                \
    acc20 = fmaf(fmaxf(a2v + c0v, 0.f), wv, acc20);                \
    acc21 = fmaf(fmaxf(a2v + c1v, 0.f), wv, acc21);                \
    acc22 = fmaf(fmaxf(a2v + c2v, 0.f), wv, acc22);

#define COMPQ(W, A0, A1, A2, C0, C1, C2)                           \
    ROW(W.x, A0.x, A1.x, A2.x, C0.x, C1.x, C2.x)                   \
    ROW(W.y, A0.y, A1.y, A2.y, C0.y, C1.y, C2.y)                   \
    ROW(W.z, A0.z, A1.z, A2.z, C0.z, C1.z, C2.z)                   \
    ROW(W.w, A0.w, A1.w, A2.w, C0.w, C1.w, C2.w)

#define LOADQ(W, A0, A1, A2, C0, C1, C2, q)                        \
    W  = *(const float4*)&w2s[hbeg + 4*(q)];                       \
    A0 = *(const float4*)&Aq[half][q][ty][0];                      \
    A1 = *(const float4*)&Aq[half][q][ty + 16][0];                 \
    A2 = *(const float4*)&Aq[half][q][ty + 32][0];                 \
    C0 = *(const float4*)&Cq[half][q][tx][0];                      \
    C1 = *(const float4*)&Cq[half][q][tx + 16][0];                 \
    C2 = *(const float4*)&Cq[half][q][tx + 32][0];

__global__ __launch_bounds__(512) void k2_pair(
    const float* __restrict__ wsf, const float* __restrict__ w2,
    const int* __restrict__ perm, const float* __restrict__ b2,
    float* __restrict__ rsO, float* __restrict__ t0c)
{
    const int tid  = threadIdx.x;
    const int half = tid >> 8;         // 0 or 1
    const int t2   = tid & 255;
    const int tx = t2 & 15;            // j: {tx, tx+16, tx+32}
    const int ty = t2 >> 4;            // i: {ty, ty+16, ty+32}
    const int j0 = blockIdx.x * 48;
    const int i0 = blockIdx.y * 48;
    const int hbeg = half * 152;       // 38 quads each; half1 top quad = pad

    const float* AF = wsf + AF_OFF;
    const float* CF = wsf + CF_OFF;

    __shared__ __align__(16) float Aq[2][38][49][4];   // [half][quad][i][4h]
    __shared__ __align__(16) float Cq[2][38][49][4];   // [half][quad][j][4h]
    __shared__ __align__(16) float w2s[304];

    if (tid < 76) {
        float4 wv = make_float4(0.f,0.f,0.f,0.f);
        if (tid < 75) wv = *(const float4*)(w2 + 4*tid);
        *(float4*)&w2s[4*tid] = wv;
    }
    // stage: per half, 48 rows x 38 quads; lanes walk q fastest => global
    // reads coalesced (608B runs); LDS writes ~5-way aliased (pad 49).
    for (int e = t2; e < 48 * 38; e += 256) {
        int i = e / 38, q = e % 38;
        float4 av = *(const float4*)(AF + (size_t)(i0 + i) * HP + hbeg + 4*q);
        float4 cv = *(const float4*)(CF + (size_t)(j0 + i) * HP + hbeg + 4*q);
        *(float4*)&Aq[half][q][i][0] = av;
        *(float4*)&Cq[half][q][i][0] = cv;
    }
    __syncthreads();

    float acc00 = 0.f, acc01 = 0.f, acc02 = 0.f;
    float acc10 = 0.f, acc11 = 0.f, acc12 = 0.f;
    float acc20 = 0.f, acc21 = 0.f, acc22 = 0.f;

    float4 w0, a00, a10, a20, c00, c10, c20;
    float4 w1, a01, a11, a21, c01, c11, c21;
    LOADQ(w0, a00, a10, a20, c00, c10, c20, 0)
    for (int q = 0; q < 36; q += 2) {
        LOADQ(w1, a01, a11, a21, c01, c11, c21, q + 1)
        COMPQ(w0, a00, a10, a20, c00, c10, c20)
        LOADQ(w0, a00, a10, a20, c00, c10, c20, q + 2)
        COMPQ(w1, a01, a11, a21, c01, c11, c21)
    }
    LOADQ(w1, a01, a11, a21, c01, c11, c21, 37)
    COMPQ(w0, a00, a10, a20, c00, c10, c20)
    COMPQ(w1, a01, a11, a21, c01, c11, c21)

    // combine halves through LDS (reuse Aq[0] region; all reads done)
    __syncthreads();
    float* comb = &Aq[0][0][0][0];     // [256][9]
    if (half) {
        float* cp = comb + t2 * 9;
        cp[0] = acc00; cp[1] = acc01; cp[2] = acc02;
        cp[3] = acc10; cp[4] = acc11; cp[5] = acc12;
        cp[6] = acc20; cp[7] = acc21; cp[8] = acc22;
    }
    __syncthreads();

    if (half == 0) {
        const float accA[3][3] = {{acc00, acc01, acc02},
                                  {acc10, acc11, acc12},
                                  {acc20, acc21, acc22}};
        const float* cp = comb + t2 * 9;
        const float b2v = b2[0];
        #pragma unroll
        for (int r = 0; r < 3; ++r) {
            int i = i0 + ty + 16 * r;
            int pj = perm[i];
            float rsum = 0.f;
            #pragma unroll
            for (int c = 0; c < 3; ++c) {
                int j = j0 + tx + 16 * c;
                float u = accA[r][c] + cp[r*3 + c] + b2v;
                rsum += expf(u);
                if (j == pj)           // exactly one thread chip-wide per row
                    t0c[i] = (u > 0.f) ? u + log1pf(expf(-u)) : log1pf(expf(u));
            }
            #pragma unroll
            for (int off = 8; off; off >>= 1)
                rsum += __shfl_xor(rsum, off, 16);
            if (tx == 0) rsO[(size_t)blockIdx.x * NN + i] = rsum;
        }
    }
}

// ================= K3: combine RS partials + final f64 reduction ============
__global__ __launch_bounds__(256) void k3_final(
    const float* __restrict__ wsf, float* __restrict__ out)
{
    const int tid = threadIdx.x;
    const float* rs = wsf + RS_OFF;
    const float* t0 = wsf + T0_OFF;

    double st0 = 0.0, slse = 0.0;
    for (int i = tid; i < NN; i += 256) {
        float s = 0.f;
        #pragma unroll
        for (int jb = 0; jb < 16; ++jb) s += rs[(size_t)jb * NN + i];
        st0  += (double)t0[i];
        slse += log((double)NN + (double)s);
    }
    __shared__ double sa[256], sb[256];
    sa[tid] = st0; sb[tid] = slse;
    __syncthreads();
    for (int s = 128; s > 0; s >>= 1) {
        if (tid < s) { sa[tid] += sa[tid+s]; sb[tid] += sb[tid+s]; }
        __syncthreads();
    }
    if (tid == 0) {
        double lb = sa[0]/(double)NN - (sb[0]/(double)NN - log((double)NN));
        out[0] = (float)lb;
    }
}

extern "C" void kernel_launch(void* const* d_in, const int* in_sizes, int n_in,
                              void* d_out, int out_size, void* d_ws, size_t ws_size,
                              hipStream_t stream) {
    const float* x    = (const float*)d_in[0];
    const float* y    = (const float*)d_in[1];
    const int*   perm = (const int*)  d_in[2];
    const float* W1   = (const float*)d_in[3];
    const float* b1   = (const float*)d_in[4];
    const float* W2   = (const float*)d_in[5];
    const float* b2   = (const float*)d_in[6];
    float* wsf = (float*)d_ws;
    float* out = (float*)d_out;

    k1_gemm    <<<dim3(6,5,8),  256, 0, stream>>>(x, y, perm, W1, wsf);
    k1b_combine<<<480,          256, 0, stream>>>(b1, wsf);
    k2_pair    <<<dim3(16,16),  512, 0, stream>>>(wsf, W2, perm, b2,
                                                  wsf + RS_OFF, wsf + T0_OFF);
    k3_final   <<<1,            256, 0, stream>>>(wsf, out);
}